// Round 1
// baseline (168.739 us; speedup 1.0000x reference)
//
#include <hip/hip_runtime.h>
#include <hip/hip_bf16.h>

#define C_ 10
#define B_ 8192
#define F_ 256
#define O_ 64
#define DK_ 5

// ---------------- K1: G[c,f] = sum_b x[b,f] * y[b,c]  (atomic partial sums) --
__global__ __launch_bounds__(256) void k1_reduce(const float* __restrict__ x,
                                                 const float* __restrict__ y,
                                                 float* __restrict__ G) {
    __shared__ float ylds[32 * C_];
    const int b0 = blockIdx.x * 32;
    const int t  = threadIdx.x;
    for (int i = t; i < 32 * C_; i += 256) ylds[i] = y[b0 * C_ + i];
    __syncthreads();

    float acc[C_];
#pragma unroll
    for (int c = 0; c < C_; ++c) acc[c] = 0.f;

    const int f = t;  // 256 threads = 256 features
    for (int b = 0; b < 32; ++b) {
        float xv = x[(b0 + b) * F_ + f];
#pragma unroll
        for (int c = 0; c < C_; ++c) acc[c] = fmaf(ylds[b * C_ + c], xv, acc[c]);
    }
#pragma unroll
    for (int c = 0; c < C_; ++c) atomicAdd(&G[c * F_ + f], acc[c]);
}

// ---------------- K2: attn2[c,f] = exp(z - max_f z) * w_value[c] ------------
// z[c,f] = s_c * G[c,f] / B ; softmax/max(softmax) == exp(z - zmax)
__global__ __launch_bounds__(256) void k2_softmax(const float* __restrict__ G,
                                                  const float* __restrict__ w_key,
                                                  const float* __restrict__ w_query,
                                                  const float* __restrict__ w_value,
                                                  float* __restrict__ attn2) {
    const int c = blockIdx.x;
    const int f = threadIdx.x;

    float s = 0.f;
#pragma unroll
    for (int k = 0; k < DK_; ++k) s += w_key[c * DK_ + k] * w_query[c * DK_ + k];

    float z = s * G[c * F_ + f] * (1.0f / (float)B_);

    // wave64 max-reduce, then cross-wave via LDS
    float m = z;
#pragma unroll
    for (int off = 32; off >= 1; off >>= 1) m = fmaxf(m, __shfl_xor(m, off));
    __shared__ float wmax[4];
    if ((threadIdx.x & 63) == 0) wmax[threadIdx.x >> 6] = m;
    __syncthreads();
    float mm = fmaxf(fmaxf(wmax[0], wmax[1]), fmaxf(wmax[2], wmax[3]));

    attn2[c * F_ + f] = expf(z - mm) * w_value[c];
}

// ---------------- K3: out[c,b,o] = x[b,:] @ (attn2[c,:] . weight[c,:,:]) + bias
// block = (c, 64-row tile), 256 threads: o = t&63, row-slot r = t>>6 (16 rows each)
__global__ __launch_bounds__(256) void k3_gemm(const float* __restrict__ x,
                                               const float* __restrict__ weight,
                                               const float* __restrict__ bias,
                                               const float* __restrict__ attn2,
                                               float* __restrict__ out) {
    __shared__ float wm[F_ * O_];  // 64 KiB: weight[c] pre-scaled by attn2[c,f]
    const int c  = blockIdx.y;
    const int b0 = blockIdx.x * 64;
    const int t  = threadIdx.x;

    // stage weight * attn2 into LDS (coalesced float4)
    const float4* wsrc = (const float4*)(weight + (size_t)c * F_ * O_);
    const float*  asrc = attn2 + c * F_;
#pragma unroll
    for (int j = 0; j < 16; ++j) {
        int i4 = t + 256 * j;          // float4 index, 4096 total
        float4 w4 = wsrc[i4];
        float  a  = asrc[i4 >> 4];     // f = (i4*4)/64
        float4 r4 = make_float4(w4.x * a, w4.y * a, w4.z * a, w4.w * a);
        ((float4*)wm)[i4] = r4;
    }
    __syncthreads();

    const int o = t & 63;
    const int r = t >> 6;  // wave-uniform

    float acc[16];
#pragma unroll
    for (int k = 0; k < 16; ++k) acc[k] = 0.f;

    const float* xbase = x + (size_t)(b0 + r * 16) * F_;
    for (int f = 0; f < F_; f += 4) {
        // conflict-free LDS reads: addr = f*64+o, lanes consecutive -> 2-way alias (free)
        float w0 = wm[(f + 0) * O_ + o];
        float w1 = wm[(f + 1) * O_ + o];
        float w2 = wm[(f + 2) * O_ + o];
        float w3 = wm[(f + 3) * O_ + o];
#pragma unroll
        for (int k = 0; k < 16; ++k) {
            float4 xv = *(const float4*)(xbase + k * F_ + f);  // wave-uniform addr -> 1 line
            float a = acc[k];
            a = fmaf(xv.x, w0, a);
            a = fmaf(xv.y, w1, a);
            a = fmaf(xv.z, w2, a);
            a = fmaf(xv.w, w3, a);
            acc[k] = a;
        }
    }

    const float bo = bias[c * O_ + o];
    float* obase = out + ((size_t)c * B_ + b0 + r * 16) * O_ + o;
#pragma unroll
    for (int k = 0; k < 16; ++k) obase[k * O_] = acc[k] + bo;
}

extern "C" void kernel_launch(void* const* d_in, const int* in_sizes, int n_in,
                              void* d_out, int out_size, void* d_ws, size_t ws_size,
                              hipStream_t stream) {
    const float* x       = (const float*)d_in[0];
    const float* y       = (const float*)d_in[1];
    const float* w_key   = (const float*)d_in[2];
    const float* w_query = (const float*)d_in[3];
    const float* w_value = (const float*)d_in[4];
    const float* weight  = (const float*)d_in[5];
    const float* bias    = (const float*)d_in[6];
    float* out = (float*)d_out;

    float* G     = (float*)d_ws;      // C_*F_ floats
    float* attn2 = G + C_ * F_;       // C_*F_ floats

    hipMemsetAsync(G, 0, C_ * F_ * sizeof(float), stream);
    k1_reduce<<<B_ / 32, 256, 0, stream>>>(x, y, G);
    k2_softmax<<<C_, 256, 0, stream>>>(G, w_key, w_query, w_value, attn2);
    dim3 g3(B_ / 64, C_);
    k3_gemm<<<g3, 256, 0, stream>>>(x, weight, bias, attn2, out);
}

// Round 2
// 36.263 us; speedup vs baseline: 4.6532x; 4.6532x over previous
//
#include <hip/hip_runtime.h>
#include <hip/hip_bf16.h>

#define C_ 10
#define B_ 8192
#define F_ 256
#define O_ 64
#define DK_ 5

typedef __attribute__((ext_vector_type(8))) short short8;
typedef __attribute__((ext_vector_type(4))) float floatx4;

static __device__ __forceinline__ unsigned short f2bf(float f) {
    union { float f; unsigned u; } v; v.f = f;
    unsigned r = v.u + 0x7fffu + ((v.u >> 16) & 1u);  // round-nearest-even
    return (unsigned short)(r >> 16);
}

// ---------------- K1: G[c,f] = sum_b x[b,f]*y[b,c] (atomics) + emit x as bf16
__global__ __launch_bounds__(256) void k1_reduce(const float* __restrict__ x,
                                                 const float* __restrict__ y,
                                                 float* __restrict__ G,
                                                 unsigned short* __restrict__ xb) {
    __shared__ float ylds[32 * C_];
    const int b0 = blockIdx.x * 32;
    const int t  = threadIdx.x;
    for (int i = t; i < 32 * C_; i += 256) ylds[i] = y[b0 * C_ + i];
    __syncthreads();

    float acc[C_];
#pragma unroll
    for (int c = 0; c < C_; ++c) acc[c] = 0.f;

    for (int b = 0; b < 32; ++b) {
        float xv = x[(size_t)(b0 + b) * F_ + t];
        xb[(size_t)(b0 + b) * F_ + t] = f2bf(xv);
#pragma unroll
        for (int c = 0; c < C_; ++c) acc[c] = fmaf(ylds[b * C_ + c], xv, acc[c]);
    }
#pragma unroll
    for (int c = 0; c < C_; ++c) atomicAdd(&G[c * F_ + t], acc[c]);
}

// ---------------- K2: softmax + weight prep, one block per c ----------------
// attn2[f] = exp(z-zmax)*w_value[c];  WT[c][o][k=f] = bf16(attn2[f]*weight[c,f,o])
// stored transposed + XOR-swizzled: byte(o,f) = o*512 + ((f*2) ^ ((o&7)<<4))
__global__ __launch_bounds__(256) void k2_wprep(const float* __restrict__ G,
                                                const float* __restrict__ w_key,
                                                const float* __restrict__ w_query,
                                                const float* __restrict__ w_value,
                                                const float* __restrict__ weight,
                                                unsigned short* __restrict__ WT) {
    __shared__ float a2[F_];
    __shared__ float wred[4];
    __shared__ unsigned short wt[O_ * F_];  // 32 KiB, swizzled [o][k]
    const int c = blockIdx.x;
    const int t = threadIdx.x;

    float s = 0.f;
#pragma unroll
    for (int k = 0; k < DK_; ++k) s += w_key[c * DK_ + k] * w_query[c * DK_ + k];

    float z = s * G[c * F_ + t] * (1.0f / (float)B_);
    float m = z;
#pragma unroll
    for (int off = 32; off >= 1; off >>= 1) m = fmaxf(m, __shfl_xor(m, off));
    if ((t & 63) == 0) wred[t >> 6] = m;
    __syncthreads();
    float mm = fmaxf(fmaxf(wred[0], wred[1]), fmaxf(wred[2], wred[3]));
    a2[t] = expf(z - mm) * w_value[c];
    __syncthreads();

    const float* wsrc = weight + (size_t)c * F_ * O_;
#pragma unroll 4
    for (int j = 0; j < 64; ++j) {
        int idx = t + 256 * j;           // coalesced read of weight[c]
        int f = idx >> 6, o = idx & 63;
        float v = wsrc[idx] * a2[f];
        int byte = o * 512 + ((f * 2) ^ ((o & 7) << 4));
        *(unsigned short*)((char*)wt + byte) = f2bf(v);
    }
    __syncthreads();

    // linear 16B copy (swizzle already baked in)
    const short8* src = (const short8*)wt;
    short8* dst = (short8*)(WT + (size_t)c * O_ * F_);
#pragma unroll
    for (int j = 0; j < 8; ++j) dst[t + 256 * j] = src[t + 256 * j];
}

// ---------------- K3: out[c][b][o] = Xbf16 @ WT[c]^T + bias, MFMA 16x16x32 ---
__global__ __launch_bounds__(256) void k3_mfma(const unsigned short* __restrict__ xb,
                                               const unsigned short* __restrict__ WT,
                                               const float* __restrict__ bias,
                                               float* __restrict__ out) {
    __shared__ unsigned short wt[O_ * F_];  // 32 KiB swizzled [o][k]
    const int c  = blockIdx.y;
    const int b0 = blockIdx.x * 128;
    const int t  = threadIdx.x;

    {   // stage WT[c] linearly (preserves swizzle)
        const short8* src = (const short8*)(WT + (size_t)c * O_ * F_);
        short8* dst = (short8*)wt;
#pragma unroll
        for (int j = 0; j < 8; ++j) dst[t + 256 * j] = src[t + 256 * j];
    }
    __syncthreads();

    const int w  = t >> 6;        // wave id: 32 rows each
    const int l  = t & 63;
    const int lr = l & 15;        // A-row / B-col / D-col lane index
    const int lg = l >> 4;        // k-group
    const int mr0 = b0 + w * 32;

    floatx4 acc[2][4];
#pragma unroll
    for (int am = 0; am < 2; ++am)
#pragma unroll
        for (int n = 0; n < 4; ++n) acc[am][n] = (floatx4){0.f, 0.f, 0.f, 0.f};

    const unsigned short* xrow0 = xb + (size_t)(mr0 + lr) * F_;
    const unsigned short* xrow1 = xb + (size_t)(mr0 + 16 + lr) * F_;

#pragma unroll
    for (int k0 = 0; k0 < 8; ++k0) {
        const int kk = k0 * 32 + lg * 8;                    // element offset in K
        short8 a0 = *(const short8*)(xrow0 + kk);           // per-lane 16B global
        short8 a1 = *(const short8*)(xrow1 + kk);
#pragma unroll
        for (int n = 0; n < 4; ++n) {
            int o = n * 16 + lr;
            int byte = o * 512 + ((k0 * 64 + lg * 16) ^ ((o & 7) << 4));
            short8 bf = *(const short8*)((const char*)wt + byte);  // ds_read_b128
            acc[0][n] = __builtin_amdgcn_mfma_f32_16x16x32_bf16(a0, bf, acc[0][n], 0, 0, 0);
            acc[1][n] = __builtin_amdgcn_mfma_f32_16x16x32_bf16(a1, bf, acc[1][n], 0, 0, 0);
        }
    }

    // D layout: col = lane&15, row = (lane>>4)*4 + reg
#pragma unroll
    for (int am = 0; am < 2; ++am) {
#pragma unroll
        for (int n = 0; n < 4; ++n) {
            int col = n * 16 + lr;
            float bo = bias[c * O_ + col];
#pragma unroll
            for (int r = 0; r < 4; ++r) {
                int row = mr0 + am * 16 + lg * 4 + r;
                out[((size_t)c * B_ + row) * O_ + col] = acc[am][n][r] + bo;
            }
        }
    }
}

extern "C" void kernel_launch(void* const* d_in, const int* in_sizes, int n_in,
                              void* d_out, int out_size, void* d_ws, size_t ws_size,
                              hipStream_t stream) {
    const float* x       = (const float*)d_in[0];
    const float* y       = (const float*)d_in[1];
    const float* w_key   = (const float*)d_in[2];
    const float* w_query = (const float*)d_in[3];
    const float* w_value = (const float*)d_in[4];
    const float* weight  = (const float*)d_in[5];
    const float* bias    = (const float*)d_in[6];
    float* out = (float*)d_out;

    char* ws = (char*)d_ws;
    float*          G  = (float*)ws;                          // 10*256 f32
    unsigned short* xb = (unsigned short*)(ws + 16384);       // 8192*256 bf16 (4 MiB)
    unsigned short* WT = (unsigned short*)(ws + 16384 + (size_t)B_ * F_ * 2);  // 10*64*256 bf16

    hipMemsetAsync(G, 0, C_ * F_ * sizeof(float), stream);
    k1_reduce<<<B_ / 32, 256, 0, stream>>>(x, y, G, xb);
    k2_wprep<<<C_, 256, 0, stream>>>(G, w_key, w_query, w_value, weight, WT);
    dim3 g3(B_ / 128, C_);
    k3_mfma<<<g3, 256, 0, stream>>>(xb, WT, bias, out);
}

// Round 3
// 34.449 us; speedup vs baseline: 4.8982x; 1.0527x over previous
//
#include <hip/hip_runtime.h>
#include <hip/hip_bf16.h>

#define C_ 10
#define B_ 8192
#define F_ 256
#define O_ 64
#define DK_ 5

typedef __attribute__((ext_vector_type(8))) short short8;
typedef __attribute__((ext_vector_type(4))) float floatx4;

static __device__ __forceinline__ unsigned short f2bf(float f) {
    union { float f; unsigned u; } v; v.f = f;
    unsigned r = v.u + 0x7fffu + ((v.u >> 16) & 1u);  // round-nearest-even
    return (unsigned short)(r >> 16);
}

// ---------------- K1: G[c,f] = sum_b x[b,f]*y[b,c] (atomics) + emit x as bf16
// float4 loads -> LDS tile + vectorized bf16 stores; per-thread 1-feature acc.
__global__ __launch_bounds__(256) void k1_reduce(const float* __restrict__ x,
                                                 const float* __restrict__ y,
                                                 float* __restrict__ G,
                                                 unsigned short* __restrict__ xb) {
    __shared__ float xl[32 * F_];      // 32 KiB
    __shared__ float yl[32 * C_];
    const int b0 = blockIdx.x * 32;
    const int t  = threadIdx.x;

    for (int i = t; i < 32 * C_; i += 256) yl[i] = y[b0 * C_ + i];

    const int r  = t >> 6;             // row sub-slot 0..3
    const int f4 = (t & 63) * 4;       // 4 features per thread
#pragma unroll
    for (int j = 0; j < 8; ++j) {
        int row = r + 4 * j;           // 0..31
        float4 v = *(const float4*)(x + (size_t)(b0 + row) * F_ + f4);
        *(float4*)(xl + row * F_ + f4) = v;
        ushort4 s;
        s.x = f2bf(v.x); s.y = f2bf(v.y); s.z = f2bf(v.z); s.w = f2bf(v.w);
        *(ushort4*)(xb + (size_t)(b0 + row) * F_ + f4) = s;
    }
    __syncthreads();

    float acc[C_];
#pragma unroll
    for (int c = 0; c < C_; ++c) acc[c] = 0.f;

#pragma unroll 8
    for (int b = 0; b < 32; ++b) {
        float xv = xl[b * F_ + t];     // lanes -> 2-way bank alias (free)
#pragma unroll
        for (int c = 0; c < C_; ++c) acc[c] = fmaf(yl[b * C_ + c], xv, acc[c]);
    }
#pragma unroll
    for (int c = 0; c < C_; ++c) atomicAdd(&G[c * F_ + t], acc[c]);
}

// ---------------- K2: softmax + weight prep. 4 blocks per c -----------------
// attn2[f] = exp(z-zmax)*w_value[c] (redundant per block);
// WT[c] swizzle-baked bf16 [o][k=f]: byte(o,f) = o*512 + ((2f) ^ ((o&7)<<4))
__global__ __launch_bounds__(256) void k2_wprep(const float* __restrict__ G,
                                                const float* __restrict__ w_key,
                                                const float* __restrict__ w_query,
                                                const float* __restrict__ w_value,
                                                const float* __restrict__ weight,
                                                unsigned short* __restrict__ WT) {
    __shared__ float a2[F_];
    __shared__ float wred[4];
    const int c    = blockIdx.x >> 2;
    const int part = blockIdx.x & 3;   // 64 features each
    const int t    = threadIdx.x;

    float s = 0.f;
#pragma unroll
    for (int k = 0; k < DK_; ++k) s += w_key[c * DK_ + k] * w_query[c * DK_ + k];

    float z = s * G[c * F_ + t] * (1.0f / (float)B_);
    float m = z;
#pragma unroll
    for (int off = 32; off >= 1; off >>= 1) m = fmaxf(m, __shfl_xor(m, off));
    if ((t & 63) == 0) wred[t >> 6] = m;
    __syncthreads();
    float mm = fmaxf(fmaxf(wred[0], wred[1]), fmaxf(wred[2], wred[3]));
    a2[t] = expf(z - mm) * w_value[c];
    __syncthreads();

    const int o  = t & 63;
    const int fg = t >> 6;
    const float* wsrc = weight + (size_t)c * F_ * O_;
    char* wdst = (char*)(WT + (size_t)c * O_ * F_);
#pragma unroll
    for (int g = 0; g < 2; ++g) {
        int f0 = part * 64 + fg * 16 + g * 8;
        short8 v8;
#pragma unroll
        for (int e = 0; e < 8; ++e) {
            int f = f0 + e;
            v8[e] = (short)f2bf(wsrc[f * O_ + o] * a2[f]);  // coalesced along o
        }
        int byte = o * 512 + ((2 * f0) ^ ((o & 7) << 4));   // 16B-aligned
        *(short8*)(wdst + byte) = v8;
    }
}

// ---------------- K3: out[c][b][o] = Xbf16 @ WT[c]^T + bias, MFMA 16x16x32 ---
// 64-row tiles, 4 waves x 16 rows, A prefetched to regs before staging barrier
__global__ __launch_bounds__(256) void k3_mfma(const unsigned short* __restrict__ xb,
                                               const unsigned short* __restrict__ WT,
                                               const float* __restrict__ bias,
                                               float* __restrict__ out) {
    __shared__ unsigned short wt[O_ * F_];  // 32 KiB swizzled [o][k]
    const int c  = blockIdx.y;
    const int b0 = blockIdx.x * 64;
    const int t  = threadIdx.x;
    const int w  = t >> 6;
    const int l  = t & 63;
    const int lr = l & 15;
    const int lg = l >> 4;

    // A prefetch: 8 x short8 (row b0+w*16+lr, k = k0*32 + lg*8), issues early
    const unsigned short* xrow = xb + (size_t)(b0 + w * 16 + lr) * F_;
    short8 a[8];
#pragma unroll
    for (int k0 = 0; k0 < 8; ++k0) a[k0] = *(const short8*)(xrow + k0 * 32 + lg * 8);

    // stage WT[c] linearly (swizzle pre-baked)
    {
        const short8* src = (const short8*)(WT + (size_t)c * O_ * F_);
        short8* dst = (short8*)wt;
#pragma unroll
        for (int j = 0; j < 8; ++j) dst[t + 256 * j] = src[t + 256 * j];
    }
    __syncthreads();

    floatx4 acc[4];
#pragma unroll
    for (int n = 0; n < 4; ++n) {
        float bo = bias[c * O_ + n * 16 + lr];
        acc[n] = (floatx4){bo, bo, bo, bo};   // bias folded into C-init
    }

#pragma unroll
    for (int k0 = 0; k0 < 8; ++k0) {
#pragma unroll
        for (int n = 0; n < 4; ++n) {
            int o = n * 16 + lr;
            int byte = o * 512 + ((k0 * 64 + lg * 16) ^ ((o & 7) << 4));
            short8 bf = *(const short8*)((const char*)wt + byte);  // conflict-free
            acc[n] = __builtin_amdgcn_mfma_f32_16x16x32_bf16(a[k0], bf, acc[n], 0, 0, 0);
        }
    }

    // D layout: col = lane&15, row = (lane>>4)*4 + reg
#pragma unroll
    for (int n = 0; n < 4; ++n) {
        int col = n * 16 + lr;
#pragma unroll
        for (int r = 0; r < 4; ++r) {
            int row = b0 + w * 16 + lg * 4 + r;
            out[((size_t)c * B_ + row) * O_ + col] = acc[n][r];
        }
    }
}

extern "C" void kernel_launch(void* const* d_in, const int* in_sizes, int n_in,
                              void* d_out, int out_size, void* d_ws, size_t ws_size,
                              hipStream_t stream) {
    const float* x       = (const float*)d_in[0];
    const float* y       = (const float*)d_in[1];
    const float* w_key   = (const float*)d_in[2];
    const float* w_query = (const float*)d_in[3];
    const float* w_value = (const float*)d_in[4];
    const float* weight  = (const float*)d_in[5];
    const float* bias    = (const float*)d_in[6];
    float* out = (float*)d_out;

    char* ws = (char*)d_ws;
    float*          G  = (float*)ws;                                           // 10 KiB
    unsigned short* xb = (unsigned short*)(ws + 16384);                        // 4 MiB
    unsigned short* WT = (unsigned short*)(ws + 16384 + (size_t)B_ * F_ * 2);  // 320 KiB

    hipMemsetAsync(G, 0, C_ * F_ * sizeof(float), stream);
    k1_reduce<<<B_ / 32, 256, 0, stream>>>(x, y, G, xb);
    k2_wprep<<<C_ * 4, 256, 0, stream>>>(G, w_key, w_query, w_value, weight, WT);
    dim3 g3(B_ / 64, C_);
    k3_mfma<<<g3, 256, 0, stream>>>(xb, WT, bias, out);
}